// Round 1
// baseline (576.648 us; speedup 1.0000x reference)
//
#include <hip/hip_runtime.h>

typedef unsigned short ushort_t;
typedef unsigned int uint_t;

#define NB_AGG 2560

__device__ __forceinline__ float bf2f(ushort_t u) {
    union { uint_t i; float f; } v; v.i = ((uint_t)u) << 16; return v.f;
}
__device__ __forceinline__ ushort_t f2bf(float f) {
    union { float f; uint_t i; } v; v.f = f;
    uint_t u = v.i;
    uint_t r = (u + 0x7fffu + ((u >> 16) & 1u)) >> 16;   // RNE
    return (ushort_t)r;
}

// ---------------------------------------------------------------- CSR build
__global__ __launch_bounds__(256) void count_k(const int* __restrict__ dst,
                                               int* __restrict__ cnt, int E) {
    for (int e = blockIdx.x * 256 + threadIdx.x; e < E; e += gridDim.x * 256)
        atomicAdd(&cnt[dst[e]], 1);
}

__global__ __launch_bounds__(256) void scanA_k(const int* __restrict__ cnt,
                                               int* __restrict__ segsum, int N) {
    int base = blockIdx.x * 1024 + threadIdx.x;
    int v = 0;
#pragma unroll
    for (int i = 0; i < 4; ++i) {
        int idx = base + i * 256;
        if (idx < N) v += cnt[idx];
    }
    __shared__ int sh[256];
    sh[threadIdx.x] = v;
    __syncthreads();
    for (int off = 128; off > 0; off >>= 1) {
        if (threadIdx.x < off) sh[threadIdx.x] += sh[threadIdx.x + off];
        __syncthreads();
    }
    if (threadIdx.x == 0) segsum[blockIdx.x] = sh[0];
}

// exclusive scan of <=128 segment sums, single block of 128 threads
__global__ void scanB_k(int* segsum, int nseg) {
    __shared__ int sh[128];
    int t = threadIdx.x;
    int own = (t < nseg) ? segsum[t] : 0;
    sh[t] = own;
    __syncthreads();
    for (int off = 1; off < 128; off <<= 1) {
        int v = (t >= off) ? sh[t - off] : 0;
        __syncthreads();
        sh[t] += v;
        __syncthreads();
    }
    if (t < nseg) segsum[t] = sh[t] - own;
}

__global__ __launch_bounds__(256) void scanC_k(const int* __restrict__ cnt,
                                               const int* __restrict__ segsum,
                                               int* __restrict__ row_ptr,
                                               int* __restrict__ cursor,
                                               float* __restrict__ dinv,
                                               int N, int E) {
    int t = threadIdx.x;
    int base = blockIdx.x * 1024 + t * 4;
    int c0 = 0, c1 = 0, c2 = 0, c3 = 0;
    if (base + 0 < N) c0 = cnt[base + 0];
    if (base + 1 < N) c1 = cnt[base + 1];
    if (base + 2 < N) c2 = cnt[base + 2];
    if (base + 3 < N) c3 = cnt[base + 3];
    int tsum = c0 + c1 + c2 + c3;
    __shared__ int sh[256];
    sh[t] = tsum;
    __syncthreads();
    for (int off = 1; off < 256; off <<= 1) {
        int v = (t >= off) ? sh[t - off] : 0;
        __syncthreads();
        sh[t] += v;
        __syncthreads();
    }
    int excl = segsum[blockIdx.x] + sh[t] - tsum;
    int p0 = excl, p1 = excl + c0, p2 = excl + c0 + c1, p3 = excl + c0 + c1 + c2;
    if (base + 0 < N) { row_ptr[base + 0] = p0; cursor[base + 0] = p0; dinv[base + 0] = rsqrtf((float)c0 + 1.0f); }
    if (base + 1 < N) { row_ptr[base + 1] = p1; cursor[base + 1] = p1; dinv[base + 1] = rsqrtf((float)c1 + 1.0f); }
    if (base + 2 < N) { row_ptr[base + 2] = p2; cursor[base + 2] = p2; dinv[base + 2] = rsqrtf((float)c2 + 1.0f); }
    if (base + 3 < N) { row_ptr[base + 3] = p3; cursor[base + 3] = p3; dinv[base + 3] = rsqrtf((float)c3 + 1.0f); }
    if (blockIdx.x == 0 && t == 0) row_ptr[N] = E;
}

__global__ __launch_bounds__(256) void fill_k(const int* __restrict__ src,
                                              const int* __restrict__ dst,
                                              int* __restrict__ cursor,
                                              int* __restrict__ colA, int E) {
    for (int e = blockIdx.x * 256 + threadIdx.x; e < E; e += gridDim.x * 256) {
        int d = dst[e];
        int pos = atomicAdd(&cursor[d], 1);
        colA[pos] = src[e];
    }
}

// ------------------------------------------------------------- GEMM (64x64)
// One thread = one row. W staged in LDS (broadcast reads). MODE==1 applies
// folded BN (a*z+c) + ReLU to the input on the fly. Output stored bf16.
template <int MODE>
__global__ __launch_bounds__(256) void gemm_k(const float* __restrict__ Z,
                                              const float* __restrict__ W,
                                              const float* __restrict__ cA,
                                              const float* __restrict__ cC,
                                              ushort_t* __restrict__ XW, int N) {
    __shared__ float Wl[64][64];
    __shared__ float Al[64], Cl[64];
    int t = threadIdx.x;
#pragma unroll
    for (int i = 0; i < 16; ++i) {
        int idx = t + i * 256;
        Wl[idx >> 6][idx & 63] = W[idx];
    }
    if (MODE && t < 64) { Al[t] = cA[t]; Cl[t] = cC[t]; }
    __syncthreads();

    int row = blockIdx.x * 256 + t;
    if (row >= N) return;
    const float4* zr = (const float4*)(Z + (size_t)row * 64);

    float acc[64];
#pragma unroll
    for (int j = 0; j < 64; ++j) acc[j] = 0.0f;

#pragma unroll
    for (int k4 = 0; k4 < 16; ++k4) {
        float4 zv = zr[k4];
        float zz[4] = {zv.x, zv.y, zv.z, zv.w};
#pragma unroll
        for (int kk = 0; kk < 4; ++kk) {
            int k = k4 * 4 + kk;
            float z = zz[kk];
            if (MODE) {
                z = Al[k] * z + Cl[k];
                z = fmaxf(z, 0.0f);
            }
            const float4* wr = (const float4*)(&Wl[k][0]);
#pragma unroll
            for (int j4 = 0; j4 < 16; ++j4) {
                float4 w = wr[j4];
                acc[j4 * 4 + 0] += z * w.x;
                acc[j4 * 4 + 1] += z * w.y;
                acc[j4 * 4 + 2] += z * w.z;
                acc[j4 * 4 + 3] += z * w.w;
            }
        }
    }

    uint4* o = (uint4*)(XW + ((size_t)row << 6));
#pragma unroll
    for (int g8 = 0; g8 < 8; ++g8) {
        uint_t p[4];
#pragma unroll
        for (int p2 = 0; p2 < 4; ++p2) {
            float a = acc[g8 * 8 + p2 * 2 + 0];
            float b = acc[g8 * 8 + p2 * 2 + 1];
            p[p2] = (uint_t)f2bf(a) | ((uint_t)f2bf(b) << 16);
        }
        uint4 v; v.x = p[0]; v.y = p[1]; v.z = p[2]; v.w = p[3];
        o[g8] = v;
    }
}

// ------------------------------------------------- aggregation + BN partials
// One wave per row; lane = column. out[n] = dinv[n]*sum_e dinv[src]*xw[src]
//                                          + dinv[n]^2*xw[n]
__global__ __launch_bounds__(256) void agg_k(const ushort_t* __restrict__ xw,
                                             const int* __restrict__ row_ptr,
                                             const int* __restrict__ colA,
                                             const float* __restrict__ dinv,
                                             float* __restrict__ OUT,
                                             float* __restrict__ pS,
                                             float* __restrict__ pQ, int N) {
    __shared__ float ssum[64], ssq[64];
    int t = threadIdx.x, lane = t & 63, wv = t >> 6;
    if (t < 64) ssum[t] = 0.0f;
    else if (t < 128) ssq[t - 64] = 0.0f;
    __syncthreads();

    float psum = 0.0f, psq = 0.0f;

    for (int row = blockIdx.x * 4 + wv; row < N; row += NB_AGG * 4) {
        int start = row_ptr[row];
        int end = row_ptr[row + 1];
        float acc = 0.0f;
        for (int base = start; base < end; base += 64) {
            int nchunk = min(64, end - base);
            int s = 0; float dv = 0.0f;
            if (base + lane < end) {
                s = colA[base + lane];
                dv = dinv[s];
            }
            int j = 0;
            for (; j + 4 <= nchunk; j += 4) {
                int s0 = __shfl(s, j + 0), s1 = __shfl(s, j + 1);
                int s2 = __shfl(s, j + 2), s3 = __shfl(s, j + 3);
                float d0 = __shfl(dv, j + 0), d1 = __shfl(dv, j + 1);
                float d2 = __shfl(dv, j + 2), d3 = __shfl(dv, j + 3);
                ushort_t u0 = xw[(s0 << 6) | lane];
                ushort_t u1 = xw[(s1 << 6) | lane];
                ushort_t u2 = xw[(s2 << 6) | lane];
                ushort_t u3 = xw[(s3 << 6) | lane];
                acc += d0 * bf2f(u0);
                acc += d1 * bf2f(u1);
                acc += d2 * bf2f(u2);
                acc += d3 * bf2f(u3);
            }
            for (; j < nchunk; ++j) {
                int sj = __shfl(s, j);
                float dj = __shfl(dv, j);
                acc += dj * bf2f(xw[(sj << 6) | lane]);
            }
        }
        float dn = dinv[row];
        float self = bf2f(xw[(row << 6) | lane]);
        float val = dn * acc + dn * dn * self;
        OUT[(size_t)row * 64 + lane] = val;
        psum += val;
        psq += val * val;
    }

    atomicAdd(&ssum[lane], psum);
    atomicAdd(&ssq[lane], psq);
    __syncthreads();
    if (t < 64) pS[(size_t)t * NB_AGG + blockIdx.x] = ssum[t];
    else if (t < 128) pQ[(size_t)(t - 64) * NB_AGG + blockIdx.x] = ssq[t - 64];
}

// --------------------------------------------------------- BN coefficients
__global__ __launch_bounds__(256) void stats_k(const float* __restrict__ pS,
                                               const float* __restrict__ pQ,
                                               const float* __restrict__ g,
                                               const float* __restrict__ be,
                                               float* __restrict__ cA,
                                               float* __restrict__ cC, int N) {
    int c = blockIdx.x, t = threadIdx.x;
    float s = 0.0f, q = 0.0f;
    for (int i = t; i < NB_AGG; i += 256) {
        s += pS[(size_t)c * NB_AGG + i];
        q += pQ[(size_t)c * NB_AGG + i];
    }
    __shared__ float rs[256], rq[256];
    rs[t] = s; rq[t] = q;
    __syncthreads();
    for (int off = 128; off > 0; off >>= 1) {
        if (t < off) { rs[t] += rs[t + off]; rq[t] += rq[t + off]; }
        __syncthreads();
    }
    if (t == 0) {
        float mu = rs[0] / (float)N;
        float var = rq[0] / (float)N - mu * mu;
        var = fmaxf(var, 0.0f);
        float inv = rsqrtf(var + 1e-5f);
        float a = g[c] * inv;
        cA[c] = a;
        cC[c] = be[c] - mu * a;
    }
}

// ----------------------------------------------------------- final BN apply
__global__ __launch_bounds__(256) void apply_k(float* __restrict__ O,
                                               const float* __restrict__ cA,
                                               const float* __restrict__ cC,
                                               int N) {
    int total = N * 16;  // float4 count
    for (int i = blockIdx.x * 256 + threadIdx.x; i < total; i += gridDim.x * 256) {
        float4 v = ((float4*)O)[i];
        int c = (i & 15) * 4;
        v.x = cA[c + 0] * v.x + cC[c + 0];
        v.y = cA[c + 1] * v.y + cC[c + 1];
        v.z = cA[c + 2] * v.z + cC[c + 2];
        v.w = cA[c + 3] * v.w + cC[c + 3];
        ((float4*)O)[i] = v;
    }
}

// ---------------------------------------------------------------------------
extern "C" void kernel_launch(void* const* d_in, const int* in_sizes, int n_in,
                              void* d_out, int out_size, void* d_ws, size_t ws_size,
                              hipStream_t stream) {
    const float* x   = (const float*)d_in[0];
    const int*   ei  = (const int*)d_in[1];
    const float* W1  = (const float*)d_in[2];
    const float* g1  = (const float*)d_in[4];
    const float* be1 = (const float*)d_in[5];
    const float* W2  = (const float*)d_in[6];
    const float* g2  = (const float*)d_in[8];
    const float* be2 = (const float*)d_in[9];
    const float* W3  = (const float*)d_in[10];
    const float* g3  = (const float*)d_in[12];
    const float* be3 = (const float*)d_in[13];

    int N = in_sizes[0] / 64;
    int E = in_sizes[1] / 2;
    const int* srcA = ei;
    const int* dstA = ei + E;

    char* w = (char*)d_ws;
    auto alloc = [&](size_t bytes) -> char* {
        char* p = w;
        w += (bytes + 255) & ~(size_t)255;
        return p;
    };
    ushort_t* xw     = (ushort_t*)alloc((size_t)N * 64 * 2);
    int*      cnt    = (int*)alloc((size_t)N * 4);
    int*      rowp   = (int*)alloc(((size_t)N + 1) * 4);
    int*      cursor = (int*)alloc((size_t)N * 4);
    float*    dinv   = (float*)alloc((size_t)N * 4);
    int*      colA   = (int*)alloc((size_t)E * 4);
    int nseg = (N + 1023) / 1024;  // <=128 (N<=131072)
    int*      segsum = (int*)alloc((size_t)nseg * 4);
    float*    pS     = (float*)alloc((size_t)64 * NB_AGG * 4);
    float*    pQ     = (float*)alloc((size_t)64 * NB_AGG * 4);
    float*    cA1 = (float*)alloc(256); float* cC1 = (float*)alloc(256);
    float*    cA2 = (float*)alloc(256); float* cC2 = (float*)alloc(256);
    float*    cA3 = (float*)alloc(256); float* cC3 = (float*)alloc(256);
    (void)ws_size; (void)n_in; (void)out_size;

    float* out = (float*)d_out;

    // ---- CSR build (once; shared by all 3 layers) ----
    hipMemsetAsync(cnt, 0, (size_t)N * 4, stream);
    count_k<<<4096, 256, 0, stream>>>(dstA, cnt, E);
    scanA_k<<<nseg, 256, 0, stream>>>(cnt, segsum, N);
    scanB_k<<<1, 128, 0, stream>>>(segsum, nseg);
    scanC_k<<<nseg, 256, 0, stream>>>(cnt, segsum, rowp, cursor, dinv, N, E);
    fill_k<<<4096, 256, 0, stream>>>(srcA, dstA, cursor, colA, E);

    int gemmGrid = (N + 255) / 256;

    // ---- layer 1 ----
    gemm_k<0><<<gemmGrid, 256, 0, stream>>>(x, W1, nullptr, nullptr, xw, N);
    agg_k<<<NB_AGG, 256, 0, stream>>>(xw, rowp, colA, dinv, out, pS, pQ, N);
    stats_k<<<64, 256, 0, stream>>>(pS, pQ, g1, be1, cA1, cC1, N);

    // ---- layer 2 ----
    gemm_k<1><<<gemmGrid, 256, 0, stream>>>(out, W2, cA1, cC1, xw, N);
    agg_k<<<NB_AGG, 256, 0, stream>>>(xw, rowp, colA, dinv, out, pS, pQ, N);
    stats_k<<<64, 256, 0, stream>>>(pS, pQ, g2, be2, cA2, cC2, N);

    // ---- layer 3 ----
    gemm_k<1><<<gemmGrid, 256, 0, stream>>>(out, W3, cA2, cC2, xw, N);
    agg_k<<<NB_AGG, 256, 0, stream>>>(xw, rowp, colA, dinv, out, pS, pQ, N);
    stats_k<<<64, 256, 0, stream>>>(pS, pQ, g3, be3, cA3, cC3, N);

    // ---- final BN (no relu) in place on d_out ----
    apply_k<<<2048, 256, 0, stream>>>(out, cA3, cC3, N);
}